// Round 13
// baseline (184.949 us; speedup 1.0000x reference)
//
#include <hip/hip_runtime.h>
#include <hip/hip_bf16.h>
#include <stdint.h>
#include <stddef.h>

#define NVOX 262144
#define CCH 128
#define BN_EPS 1e-3f

typedef __attribute__((ext_vector_type(8))) short bfrag;   // 8 bf16 = 4 VGPRs
typedef __attribute__((ext_vector_type(4))) float f4;      // 4 f32

#define AS1 __attribute__((address_space(1)))
#define AS3 __attribute__((address_space(3)))

__device__ __forceinline__ unsigned short f2bf(float f) {
  union { float f; unsigned u; } v; v.f = f;
  unsigned r = v.u + 0x7fffu + ((v.u >> 16) & 1u);   // RNE (inputs finite)
  return (unsigned short)(r >> 16);
}

__device__ __forceinline__ bfrag pack8(f4 x, f4 y) {
  bfrag r;
  r[0] = (short)f2bf(x[0]); r[1] = (short)f2bf(x[1]);
  r[2] = (short)f2bf(x[2]); r[3] = (short)f2bf(x[3]);
  r[4] = (short)f2bf(y[0]); r[5] = (short)f2bf(y[1]);
  r[6] = (short)f2bf(y[2]); r[7] = (short)f2bf(y[3]);
  return r;
}

__device__ __forceinline__ float sigmoidf_(float x) {
  return 1.f / (1.f + __expf(-x));
}

__device__ __forceinline__ float bf2f(unsigned short h) {
  union { unsigned u; float f; } v; v.u = ((unsigned)h) << 16; return v.f;
}

// ---------------------------------------------------------------------------
// Pre-swizzle W1/W2/W3 into MFMA B-fragment order, bf16:
// region r = conv*3+tap (conv: 0=W1, 1=W2, 2=W3); frag = (r*4 + kc)*8 + tile
// lane holds B[k = kc*32 + (lane>>4)*8 + e][col = tile*16 + (lane&15)]
// ---------------------------------------------------------------------------
__global__ void prep_wfrag(const float* __restrict__ W1, const float* __restrict__ W2,
                           const float* __restrict__ W3, unsigned short* __restrict__ wf) {
  const int frag = blockIdx.x;           // 0..287
  const int tile = frag & 7;
  const int kc   = (frag >> 3) & 3;
  const int tap  = (frag >> 5) % 3;
  const int conv = frag / 96;
  const float* W = (conv == 0) ? W1 : ((conv == 1) ? W2 : W3);
  const int l   = threadIdx.x;           // 0..63
  const int col = tile * 16 + (l & 15);
  const int k0  = kc * 32 + (l >> 4) * 8;
  bfrag o;
#pragma unroll
  for (int e = 0; e < 8; ++e)
    o[e] = (short)f2bf(W[(size_t)(tap * CCH + k0 + e) * CCH + col]);
  *reinterpret_cast<bfrag*>(wf + (size_t)frag * 512 + l * 8) = o;
}

// ---------------------------------------------------------------------------
// BN scale/shift tables: bn[6][128] = {sc0, sh0, sc2, sh2, sc3, sh3}
// ---------------------------------------------------------------------------
__global__ void prep_bn(const float* g0, const float* b0, const float* m0, const float* v0,
                        const float* g2, const float* b2, const float* m2, const float* v2,
                        const float* g3, const float* b3, const float* m3, const float* v3,
                        float* __restrict__ bn) {
  const int c = threadIdx.x;
  const float s0 = g0[c] * rsqrtf(v0[c] + BN_EPS);
  const float s2 = g2[c] * rsqrtf(v2[c] + BN_EPS);
  const float s3 = g3[c] * rsqrtf(v3[c] + BN_EPS);
  bn[0 * CCH + c] = s0; bn[1 * CCH + c] = b0[c] - m0[c] * s0;
  bn[2 * CCH + c] = s2; bn[3 * CCH + c] = b2[c] - m2[c] * s2;
  bn[4 * CCH + c] = s3; bn[5 * CCH + c] = b3[c] - m3[c] * s3;
}

// ---------------------------------------------------------------------------
// Features fp32 -> bf16 (row N = zeros, the sentinel row)
// ---------------------------------------------------------------------------
__global__ void prep_bf16(const float* __restrict__ feats, unsigned short* __restrict__ fbf) {
  const size_t base = ((size_t)blockIdx.x * 256 + threadIdx.x) * 8;
  const f4 x = *reinterpret_cast<const f4*>(feats + base);
  const f4 y = *reinterpret_cast<const f4*>(feats + base + 4);
  *reinterpret_cast<bfrag*>(fbf + base) = pack8(x, y);
  if (blockIdx.x == 0 && threadIdx.x < 16) {
    bfrag z = {0, 0, 0, 0, 0, 0, 0, 0};
    *reinterpret_cast<bfrag*>(fbf + (size_t)NVOX * CCH + threadIdx.x * 8) = z;
  }
}

// ---------------------------------------------------------------------------
// v13 = v12 with the register cap fixed: __launch_bounds__(512, 2) -> VGPR cap
// 128 (2nd arg behaves as min-BLOCKS/CU on this toolchain: v10/v12 proved
// (512,6)->40, (512,4)->64). Body needs ~120 -> fits, no spill.
// Structure: 512 threads = 8 waves x (32 rows x 64 cols), block spans 256 rows;
// B per conv in 48 KB LDS; each B ds_read_b128 feeds TWO MFMAs; combined-tile
// wave-uniform sparsity skip; natural block mapping (v11's, cache-proven).
// ---------------------------------------------------------------------------
__global__ __launch_bounds__(512, 2)
void recon_v13(const unsigned short* __restrict__ fbf,
               const unsigned short* __restrict__ wfrag,
               const float* __restrict__ bn,
               const int* __restrict__ nbrz, const int* __restrict__ nbrx,
               const int* __restrict__ nbry,
               float* __restrict__ out) {
  __shared__ unsigned short Bb[24576];   // 48 KB: 3 slots x 16 frags x 1 KB

  const int tid  = threadIdx.x;
  const int lane = tid & 63;
  const int w    = tid >> 6;        // wave 0..7
  const int l15  = lane & 15;
  const int lhi  = lane >> 4;       // 0..3
  const int cb   = blockIdx.x & 1;  // 64-col half
  const int row0 = (blockIdx.x >> 1) << 8;  // *256
  const int wrow = row0 + w * 32;

  // Fill the 3 resident slots for one conv (region base RB: W1=0, W2=3, W3=6).
  auto fillconv = [&](int RB) {
#pragma unroll
    for (int i = 0; i < 6; ++i) {
      const int L    = w * 6 + i;        // local frag 0..47
      const int slot = L >> 4;           // tap 0..2
      const int sub  = L & 15;           // kc*4+ct
      const int g    = ((RB + slot) * 4 + (sub >> 2)) * 8 + cb * 4 + (sub & 3);
      __builtin_amdgcn_global_load_lds(
          (const AS1 void*)(wfrag + (size_t)g * 512 + lane * 8),
          (AS3 void*)((char*)Bb + L * 1024), 16, 0, 0);
    }
  };

  // ---- prologue: conv-z fill + neighbor indices for both row tiles ----
  fillconv(0);
  const int rowA = wrow + l15;
  const int rowB = rowA + 16;
  const int rgA = rowA * 3, rgB = rowB * 3;
  const int izpA = nbrz[rgA + 0], iznA = nbrz[rgA + 2];
  const int izpB = nbrz[rgB + 0], iznB = nbrz[rgB + 2];
  const int ixpA = nbrx[rgA + 0], ixnA = nbrx[rgA + 2];
  const int ixpB = nbrx[rgB + 0], ixnB = nbrx[rgB + 2];
  const int iypA = nbry[rgA + 0], iynA = nbry[rgA + 2];
  const int iypB = nbry[rgB + 0], iynB = nbry[rgB + 2];

  const bool azp = __any((izpA != NVOX) || (izpB != NVOX));
  const bool azn = __any((iznA != NVOX) || (iznB != NVOX));
  const bool axp = __any((ixpA != NVOX) || (ixpB != NVOX));
  const bool axn = __any((ixnA != NVOX) || (ixnB != NVOX));
  const bool ayp = __any((iypA != NVOX) || (iypB != NVOX));
  const bool ayn = __any((iynA != NVOX) || (iynB != NVOX));

  bfrag aX[4], aY[4];   // A fragments for the two row-tiles (transient)

#define LOADF(DST, IDX) {                                                     \
    const char* p = (const char*)fbf + ((size_t)(unsigned)(IDX) << 8) + (lhi << 4); \
    DST[0] = *reinterpret_cast<const bfrag*>(p);                              \
    DST[1] = *reinterpret_cast<const bfrag*>(p + 64);                         \
    DST[2] = *reinterpret_cast<const bfrag*>(p + 128);                        \
    DST[3] = *reinterpret_cast<const bfrag*>(p + 192);                        \
  }

  // one B ds_read feeds both row-tiles' MFMAs
#define TAP2(SLOT, A0, A1) {                                                  \
    const char* bs = (const char*)Bb + (SLOT) * 16384 + lane * 16;            \
    _Pragma("unroll")                                                         \
    for (int kc = 0; kc < 4; ++kc) {                                          \
      _Pragma("unroll")                                                       \
      for (int ct = 0; ct < 4; ++ct) {                                        \
        const bfrag b = *reinterpret_cast<const bfrag*>(                      \
            bs + (kc * 4 + ct) * 1024);                                       \
        A0[ct] = __builtin_amdgcn_mfma_f32_16x16x32_bf16(aX[kc], b, A0[ct], 0, 0, 0); \
        A1[ct] = __builtin_amdgcn_mfma_f32_16x16x32_bf16(aY[kc], b, A1[ct], 0, 0, 0); \
      } } }

  // One conv: (prev, self, next); self rows reloaded per conv (L2-hot).
#define CONV(VP, VN, IPA, IPB, INA, INB, A0, A1)                              \
  {                                                                           \
    if (VP) { LOADF(aX, IPA)  LOADF(aY, IPB)  TAP2(0, A0, A1) }               \
    LOADF(aX, rowA)  LOADF(aY, rowB)  TAP2(1, A0, A1)                         \
    if (VN) { LOADF(aX, INA)  LOADF(aY, INB)  TAP2(2, A0, A1) }               \
  }

  __syncthreads();   // conv-z B ready (syncthreads drains the load-lds queue)

  f4 acc0[4], acc1[4], run0[4], run1[4];
#pragma unroll
  for (int ct = 0; ct < 4; ++ct) {
    acc0[ct] = f4{0.f, 0.f, 0.f, 0.f};
    acc1[ct] = f4{0.f, 0.f, 0.f, 0.f};
  }

  // ================= conv-z (W1) =================
  CONV(azp, azn, izpA, izpB, iznA, iznB, acc0, acc1)
  __syncthreads();            // conv-z B readers done
  fillconv(6);                // issue conv-x (W3) fill; fold hides latency
  // fold: run = sigmoid(bn2(sigmoid(bn0(acc)))); acc = 0
#pragma unroll
  for (int ct = 0; ct < 4; ++ct) {
    const int col = cb * 64 + ct * 16 + l15;
    const float sc0 = bn[0 * CCH + col], sh0 = bn[1 * CCH + col];
    const float sc2 = bn[2 * CCH + col], sh2 = bn[3 * CCH + col];
#pragma unroll
    for (int j = 0; j < 4; ++j) {
      const float u0 = sigmoidf_(sc0 * acc0[ct][j] + sh0);
      run0[ct][j] = sigmoidf_(sc2 * u0 + sh2);
      const float u1 = sigmoidf_(sc0 * acc1[ct][j] + sh0);
      run1[ct][j] = sigmoidf_(sc2 * u1 + sh2);
    }
    acc0[ct] = f4{0.f, 0.f, 0.f, 0.f};
    acc1[ct] = f4{0.f, 0.f, 0.f, 0.f};
  }
  __syncthreads();            // conv-x B ready

  // ================= conv-x (W3) =================
  CONV(axp, axn, ixpA, ixpB, ixnA, ixnB, acc0, acc1)
  __syncthreads();            // conv-x B readers done
  fillconv(3);                // issue conv-y (W2) fill
  // fold: run += sigmoid(bn3(acc))
#pragma unroll
  for (int ct = 0; ct < 4; ++ct) {
    const int col = cb * 64 + ct * 16 + l15;
    const float sc3 = bn[4 * CCH + col], sh3 = bn[5 * CCH + col];
#pragma unroll
    for (int j = 0; j < 4; ++j) {
      run0[ct][j] += sigmoidf_(sc3 * acc0[ct][j] + sh3);
      run1[ct][j] += sigmoidf_(sc3 * acc1[ct][j] + sh3);
    }
  }
  __syncthreads();            // conv-y B ready

  // ================= conv-y (W2), raw into run =================
  CONV(ayp, ayn, iypA, iypB, iynA, iynB, run0, run1)

#undef CONV
#undef TAP2
#undef LOADF

  // ---- epilogue: multiply by features (bf16, cache-hot), store fp32 ----
#pragma unroll
  for (int ct = 0; ct < 4; ++ct) {
    const int col = cb * 64 + ct * 16 + l15;
#pragma unroll
    for (int j = 0; j < 4; ++j) {
      const int r0 = wrow + (lhi << 2) + j;
      const size_t o0 = ((size_t)r0 << 7) + col;
      out[o0] = run0[ct][j] * bf2f(fbf[o0]);
      const int r1 = r0 + 16;
      const size_t o1 = ((size_t)r1 << 7) + col;
      out[o1] = run1[ct][j] * bf2f(fbf[o1]);
    }
  }
}

// ---------------------------------------------------------------------------
// Last-resort fallback: exact fp32
// ---------------------------------------------------------------------------
__global__ void recon_naive(const float* __restrict__ feats,
    const float* __restrict__ W1, const float* __restrict__ W2, const float* __restrict__ W3,
    const int* __restrict__ nbrz, const int* __restrict__ nbry, const int* __restrict__ nbrx,
    const float* g0, const float* b0, const float* m0, const float* v0,
    const float* g2, const float* b2, const float* m2, const float* v2,
    const float* g3, const float* b3, const float* m3, const float* v3,
    float* __restrict__ out) {
  __shared__ float rows[3][CCH];
  const int n = blockIdx.x;
  const int d = threadIdx.x;
  float res[3];
#pragma unroll
  for (int conv = 0; conv < 3; ++conv) {
    const int* nbr  = (conv == 0) ? nbrz : ((conv == 1) ? nbry : nbrx);
    const float* W  = (conv == 0) ? W1 : ((conv == 1) ? W2 : W3);
#pragma unroll
    for (int tap = 0; tap < 3; ++tap) {
      const int idx = nbr[n * 3 + tap];
      rows[tap][d] = ((unsigned)idx < (unsigned)NVOX) ? feats[((size_t)idx << 7) + d] : 0.f;
    }
    __syncthreads();
    const float* rflat = &rows[0][0];
    float s = 0.f;
    for (int k = 0; k < 3 * CCH; ++k) s += rflat[k] * W[(size_t)k * CCH + d];
    res[conv] = s;
    __syncthreads();
  }
  const float sc0 = g0[d] * rsqrtf(v0[d] + BN_EPS), sh0 = b0[d] - m0[d] * sc0;
  const float sc2 = g2[d] * rsqrtf(v2[d] + BN_EPS), sh2 = b2[d] - m2[d] * sc2;
  const float sc3 = g3[d] * rsqrtf(v3[d] + BN_EPS), sh3 = b3[d] - m3[d] * sc3;
  float u = sigmoidf_(sc0 * res[0] + sh0);
  u = sigmoidf_(sc2 * u + sh2);
  const float s3v = sigmoidf_(sc3 * res[2] + sh3);
  out[((size_t)n << 7) + d] = (u + res[1] + s3v) * feats[((size_t)n << 7) + d];
}

extern "C" void kernel_launch(void* const* d_in, const int* in_sizes, int n_in,
                              void* d_out, int out_size, void* d_ws, size_t ws_size,
                              hipStream_t stream) {
  const float* feats = (const float*)d_in[0];
  const float* W1 = (const float*)d_in[1];
  const float* W2 = (const float*)d_in[2];
  const float* W3 = (const float*)d_in[3];
  const float* g0 = (const float*)d_in[4];
  const float* b0 = (const float*)d_in[5];
  const float* m0 = (const float*)d_in[6];
  const float* v0 = (const float*)d_in[7];
  const float* g2 = (const float*)d_in[8];
  const float* b2 = (const float*)d_in[9];
  const float* m2 = (const float*)d_in[10];
  const float* v2 = (const float*)d_in[11];
  const float* g3 = (const float*)d_in[12];
  const float* b3 = (const float*)d_in[13];
  const float* m3 = (const float*)d_in[14];
  const float* v3 = (const float*)d_in[15];
  const int* nz = (const int*)d_in[16];
  const int* ny = (const int*)d_in[17];
  const int* nx = (const int*)d_in[18];
  float* out = (float*)d_out;

  const size_t wf_bytes = 288u * 1024u;                              // 294912
  const size_t bn_bytes = 4096u;                                     // 6*128*4 padded
  const size_t fb_bytes = ((size_t)NVOX + 1) * CCH * sizeof(short);  // 67.1 MB
  if (ws_size >= wf_bytes + bn_bytes + fb_bytes) {
    unsigned short* wf  = (unsigned short*)d_ws;
    float*          bnt = (float*)((char*)d_ws + wf_bytes);
    unsigned short* fbf = (unsigned short*)((char*)d_ws + wf_bytes + bn_bytes);
    hipLaunchKernelGGL(prep_wfrag, dim3(288), dim3(64), 0, stream, W1, W2, W3, wf);
    hipLaunchKernelGGL(prep_bn, dim3(1), dim3(CCH), 0, stream,
                       g0, b0, m0, v0, g2, b2, m2, v2, g3, b3, m3, v3, bnt);
    hipLaunchKernelGGL(prep_bf16, dim3((NVOX * CCH) / (256 * 8)), dim3(256), 0, stream,
                       feats, fbf);
    hipLaunchKernelGGL(recon_v13, dim3((NVOX / 256) * 2), dim3(512), 0, stream,
                       fbf, wf, bnt, nz, nx, ny, out);
  } else {
    hipLaunchKernelGGL(recon_naive, dim3(NVOX), dim3(CCH), 0, stream,
                       feats, W1, W2, W3, nz, ny, nx,
                       g0, b0, m0, v0, g2, b2, m2, v2, g3, b3, m3, v3, out);
  }
}

// Round 14
// 162.224 us; speedup vs baseline: 1.1401x; 1.1401x over previous
//
#include <hip/hip_runtime.h>
#include <hip/hip_bf16.h>
#include <stdint.h>
#include <stddef.h>

#define NVOX 262144
#define CCH 128
#define BN_EPS 1e-3f

typedef __attribute__((ext_vector_type(8))) short bfrag;   // 8 bf16 = 4 VGPRs
typedef __attribute__((ext_vector_type(4))) float f4;      // 4 f32

#define AS1 __attribute__((address_space(1)))
#define AS3 __attribute__((address_space(3)))

__device__ __forceinline__ unsigned short f2bf(float f) {
  union { float f; unsigned u; } v; v.f = f;
  unsigned r = v.u + 0x7fffu + ((v.u >> 16) & 1u);   // RNE (inputs finite)
  return (unsigned short)(r >> 16);
}

__device__ __forceinline__ bfrag pack8(f4 x, f4 y) {
  bfrag r;
  r[0] = (short)f2bf(x[0]); r[1] = (short)f2bf(x[1]);
  r[2] = (short)f2bf(x[2]); r[3] = (short)f2bf(x[3]);
  r[4] = (short)f2bf(y[0]); r[5] = (short)f2bf(y[1]);
  r[6] = (short)f2bf(y[2]); r[7] = (short)f2bf(y[3]);
  return r;
}

__device__ __forceinline__ float sigmoidf_(float x) {
  return 1.f / (1.f + __expf(-x));
}

__device__ __forceinline__ float bf2f(unsigned short h) {
  union { unsigned u; float f; } v; v.u = ((unsigned)h) << 16; return v.f;
}

// ---------------------------------------------------------------------------
// Pre-swizzle W1/W2/W3 into MFMA B-fragment order, bf16:
// region r = conv*3+tap (conv: 0=W1, 1=W2, 2=W3); frag = (r*4 + kc)*8 + tile
// lane holds B[k = kc*32 + (lane>>4)*8 + e][col = tile*16 + (lane&15)]
// ---------------------------------------------------------------------------
__global__ void prep_wfrag(const float* __restrict__ W1, const float* __restrict__ W2,
                           const float* __restrict__ W3, unsigned short* __restrict__ wf) {
  const int frag = blockIdx.x;           // 0..287
  const int tile = frag & 7;
  const int kc   = (frag >> 3) & 3;
  const int tap  = (frag >> 5) % 3;
  const int conv = frag / 96;
  const float* W = (conv == 0) ? W1 : ((conv == 1) ? W2 : W3);
  const int l   = threadIdx.x;           // 0..63
  const int col = tile * 16 + (l & 15);
  const int k0  = kc * 32 + (l >> 4) * 8;
  bfrag o;
#pragma unroll
  for (int e = 0; e < 8; ++e)
    o[e] = (short)f2bf(W[(size_t)(tap * CCH + k0 + e) * CCH + col]);
  *reinterpret_cast<bfrag*>(wf + (size_t)frag * 512 + l * 8) = o;
}

// ---------------------------------------------------------------------------
// BN scale/shift tables: bn[6][128] = {sc0, sh0, sc2, sh2, sc3, sh3}
// ---------------------------------------------------------------------------
__global__ void prep_bn(const float* g0, const float* b0, const float* m0, const float* v0,
                        const float* g2, const float* b2, const float* m2, const float* v2,
                        const float* g3, const float* b3, const float* m3, const float* v3,
                        float* __restrict__ bn) {
  const int c = threadIdx.x;
  const float s0 = g0[c] * rsqrtf(v0[c] + BN_EPS);
  const float s2 = g2[c] * rsqrtf(v2[c] + BN_EPS);
  const float s3 = g3[c] * rsqrtf(v3[c] + BN_EPS);
  bn[0 * CCH + c] = s0; bn[1 * CCH + c] = b0[c] - m0[c] * s0;
  bn[2 * CCH + c] = s2; bn[3 * CCH + c] = b2[c] - m2[c] * s2;
  bn[4 * CCH + c] = s3; bn[5 * CCH + c] = b3[c] - m3[c] * s3;
}

// ---------------------------------------------------------------------------
// Features fp32 -> bf16 (row N = zeros, the sentinel row)
// ---------------------------------------------------------------------------
__global__ void prep_bf16(const float* __restrict__ feats, unsigned short* __restrict__ fbf) {
  const size_t base = ((size_t)blockIdx.x * 256 + threadIdx.x) * 8;
  const f4 x = *reinterpret_cast<const f4*>(feats + base);
  const f4 y = *reinterpret_cast<const f4*>(feats + base + 4);
  *reinterpret_cast<bfrag*>(fbf + base) = pack8(x, y);
  if (blockIdx.x == 0 && threadIdx.x < 16) {
    bfrag z = {0, 0, 0, 0, 0, 0, 0, 0};
    *reinterpret_cast<bfrag*>(fbf + (size_t)NVOX * CCH + threadIdx.x * 8) = z;
  }
}

// ---------------------------------------------------------------------------
// v14 = v11's exact per-wave body at 8 waves/SIMD:
// 1024-thread blocks = 16 waves x (16 rows x 64 cols) = 256 rows/block.
// B per conv in 48 KB LDS (refilled twice); __launch_bounds__(1024, 2) ->
// VGPR cap 64 (v11 proved the body fits in 60; v8's failure was cap 32).
// 2 blocks/CU x 16 waves = 32 waves/CU = 8 waves/SIMD (wave-slot capped) --
// double v11's measured TLP against gather-latency tails.
// Wave-uniform sparsity skip; first-valid off-center gather preissued before
// the self tap; folded activations; bf16 feature mirror + epilogue.
// ---------------------------------------------------------------------------
__global__ __launch_bounds__(1024, 2)
void recon_v14(const unsigned short* __restrict__ fbf,
               const unsigned short* __restrict__ wfrag,
               const float* __restrict__ bn,
               const int* __restrict__ nbrz, const int* __restrict__ nbrx,
               const int* __restrict__ nbry,
               float* __restrict__ out) {
  __shared__ unsigned short Bb[24576];   // 48 KB: 3 slots x 16 frags x 1 KB

  const int tid  = threadIdx.x;
  const int lane = tid & 63;
  const int w    = tid >> 6;        // wave 0..15
  const int l15  = lane & 15;
  const int lhi  = lane >> 4;       // 0..3
  const int cb   = blockIdx.x & 1;  // 64-col half
  const int row0 = (blockIdx.x >> 1) << 8;  // *256
  const int wrow = row0 + w * 16;

  // Fill the 3 resident slots for one conv (region base RB: W1=0, W2=3, W3=6).
  // 48 fragments of 1 KB; wave w copies fragments w*3 .. w*3+2.
  auto fillconv = [&](int RB) {
#pragma unroll
    for (int i = 0; i < 3; ++i) {
      const int L    = w * 3 + i;        // local frag 0..47
      const int slot = L >> 4;           // tap 0..2
      const int sub  = L & 15;           // kc*4+ct
      const int g    = ((RB + slot) * 4 + (sub >> 2)) * 8 + cb * 4 + (sub & 3);
      __builtin_amdgcn_global_load_lds(
          (const AS1 void*)(wfrag + (size_t)g * 512 + lane * 8),
          (AS3 void*)((char*)Bb + L * 1024), 16, 0, 0);
    }
  };

  // ---- prologue: conv-z fill + neighbor indices + self-row fragments ----
  fillconv(0);
  const int row = wrow + l15;
  const int rg  = row * 3;
  const int izp = nbrz[rg + 0], izn = nbrz[rg + 2];
  const int ixp = nbrx[rg + 0], ixn = nbrx[rg + 2];
  const int iyp = nbry[rg + 0], iyn = nbry[rg + 2];

  const bool azp = __any(izp != NVOX), azn = __any(izn != NVOX);
  const bool axp = __any(ixp != NVOX), axn = __any(ixn != NVOX);
  const bool ayp = __any(iyp != NVOX), ayn = __any(iyn != NVOX);

  bfrag aF[4];   // gathered-neighbor fragments
  bfrag aS[4];   // self-row fragments (reused by all 3 center taps)

#define LOADF(DST, IDX) {                                                     \
    const char* p = (const char*)fbf + ((size_t)(unsigned)(IDX) << 8) + (lhi << 4); \
    DST[0] = *reinterpret_cast<const bfrag*>(p);                              \
    DST[1] = *reinterpret_cast<const bfrag*>(p + 64);                         \
    DST[2] = *reinterpret_cast<const bfrag*>(p + 128);                        \
    DST[3] = *reinterpret_cast<const bfrag*>(p + 192);                        \
  }

#define TAP(SLOT, AFR, ACCS) {                                                \
    const char* bs = (const char*)Bb + (SLOT) * 16384 + lane * 16;            \
    _Pragma("unroll")                                                         \
    for (int kc = 0; kc < 4; ++kc) {                                          \
      _Pragma("unroll")                                                       \
      for (int ct = 0; ct < 4; ++ct) {                                        \
        const bfrag b = *reinterpret_cast<const bfrag*>(                      \
            bs + (kc * 4 + ct) * 1024);                                       \
        ACCS[ct] = __builtin_amdgcn_mfma_f32_16x16x32_bf16(                   \
            AFR[kc], b, ACCS[ct], 0, 0, 0);                                   \
      } } }

  // One conv: preload first valid off-center; self tap covers its latency.
#define CONV(VP, VN, IP, IN, ACCS)                                            \
  {                                                                           \
    if (VP)      LOADF(aF, IP)                                                \
    else if (VN) LOADF(aF, IN)                                                \
    TAP(1, aS, ACCS)                                                          \
    if (VP) {                                                                 \
      TAP(0, aF, ACCS)                                                        \
      if (VN) { LOADF(aF, IN)  TAP(2, aF, ACCS) }                             \
    } else if (VN) {                                                          \
      TAP(2, aF, ACCS)                                                        \
    }                                                                         \
  }

  LOADF(aS, row)   // self row (sentinel-free), reused by the 3 center taps

  __syncthreads();   // conv-z B ready (syncthreads drains the load-lds queue)

  f4 acc[4], run[4];
#pragma unroll
  for (int ct = 0; ct < 4; ++ct) {
    acc[ct] = f4{0.f, 0.f, 0.f, 0.f};
    run[ct] = f4{0.f, 0.f, 0.f, 0.f};
  }

  // ================= conv-z (W1) =================
  CONV(azp, azn, izp, izn, acc)
  __syncthreads();            // conv-z B readers done
  fillconv(6);                // issue conv-x (W3) fill; fold hides some latency
  // fold: run = sigmoid(bn2(sigmoid(bn0(acc)))); acc = 0
#pragma unroll
  for (int ct = 0; ct < 4; ++ct) {
    const int col = cb * 64 + ct * 16 + l15;
    const float sc0 = bn[0 * CCH + col], sh0 = bn[1 * CCH + col];
    const float sc2 = bn[2 * CCH + col], sh2 = bn[3 * CCH + col];
#pragma unroll
    for (int j = 0; j < 4; ++j) {
      const float u = sigmoidf_(sc0 * acc[ct][j] + sh0);
      run[ct][j] = sigmoidf_(sc2 * u + sh2);
    }
    acc[ct] = f4{0.f, 0.f, 0.f, 0.f};
  }
  __syncthreads();            // conv-x B ready

  // ================= conv-x (W3) =================
  CONV(axp, axn, ixp, ixn, acc)
  __syncthreads();            // conv-x B readers done
  fillconv(3);                // issue conv-y (W2) fill
  // fold: run += sigmoid(bn3(acc))
#pragma unroll
  for (int ct = 0; ct < 4; ++ct) {
    const int col = cb * 64 + ct * 16 + l15;
    const float sc3 = bn[4 * CCH + col], sh3 = bn[5 * CCH + col];
#pragma unroll
    for (int j = 0; j < 4; ++j)
      run[ct][j] += sigmoidf_(sc3 * acc[ct][j] + sh3);
  }
  __syncthreads();            // conv-y B ready

  // ================= conv-y (W2), raw into run =================
  CONV(ayp, ayn, iyp, iyn, run)

#undef CONV
#undef TAP
#undef LOADF

  // ---- epilogue: multiply by features (bf16, cache-hot), store fp32 ----
#pragma unroll
  for (int ct = 0; ct < 4; ++ct) {
    const int col = cb * 64 + ct * 16 + l15;
#pragma unroll
    for (int j = 0; j < 4; ++j) {
      const int r = wrow + (lhi << 2) + j;
      const size_t o = ((size_t)r << 7) + col;
      out[o] = run[ct][j] * bf2f(fbf[o]);
    }
  }
}

// ---------------------------------------------------------------------------
// Last-resort fallback: exact fp32
// ---------------------------------------------------------------------------
__global__ void recon_naive(const float* __restrict__ feats,
    const float* __restrict__ W1, const float* __restrict__ W2, const float* __restrict__ W3,
    const int* __restrict__ nbrz, const int* __restrict__ nbry, const int* __restrict__ nbrx,
    const float* g0, const float* b0, const float* m0, const float* v0,
    const float* g2, const float* b2, const float* m2, const float* v2,
    const float* g3, const float* b3, const float* m3, const float* v3,
    float* __restrict__ out) {
  __shared__ float rows[3][CCH];
  const int n = blockIdx.x;
  const int d = threadIdx.x;
  float res[3];
#pragma unroll
  for (int conv = 0; conv < 3; ++conv) {
    const int* nbr  = (conv == 0) ? nbrz : ((conv == 1) ? nbry : nbrx);
    const float* W  = (conv == 0) ? W1 : ((conv == 1) ? W2 : W3);
#pragma unroll
    for (int tap = 0; tap < 3; ++tap) {
      const int idx = nbr[n * 3 + tap];
      rows[tap][d] = ((unsigned)idx < (unsigned)NVOX) ? feats[((size_t)idx << 7) + d] : 0.f;
    }
    __syncthreads();
    const float* rflat = &rows[0][0];
    float s = 0.f;
    for (int k = 0; k < 3 * CCH; ++k) s += rflat[k] * W[(size_t)k * CCH + d];
    res[conv] = s;
    __syncthreads();
  }
  const float sc0 = g0[d] * rsqrtf(v0[d] + BN_EPS), sh0 = b0[d] - m0[d] * sc0;
  const float sc2 = g2[d] * rsqrtf(v2[d] + BN_EPS), sh2 = b2[d] - m2[d] * sc2;
  const float sc3 = g3[d] * rsqrtf(v3[d] + BN_EPS), sh3 = b3[d] - m3[d] * sc3;
  float u = sigmoidf_(sc0 * res[0] + sh0);
  u = sigmoidf_(sc2 * u + sh2);
  const float s3v = sigmoidf_(sc3 * res[2] + sh3);
  out[((size_t)n << 7) + d] = (u + res[1] + s3v) * feats[((size_t)n << 7) + d];
}

extern "C" void kernel_launch(void* const* d_in, const int* in_sizes, int n_in,
                              void* d_out, int out_size, void* d_ws, size_t ws_size,
                              hipStream_t stream) {
  const float* feats = (const float*)d_in[0];
  const float* W1 = (const float*)d_in[1];
  const float* W2 = (const float*)d_in[2];
  const float* W3 = (const float*)d_in[3];
  const float* g0 = (const float*)d_in[4];
  const float* b0 = (const float*)d_in[5];
  const float* m0 = (const float*)d_in[6];
  const float* v0 = (const float*)d_in[7];
  const float* g2 = (const float*)d_in[8];
  const float* b2 = (const float*)d_in[9];
  const float* m2 = (const float*)d_in[10];
  const float* v2 = (const float*)d_in[11];
  const float* g3 = (const float*)d_in[12];
  const float* b3 = (const float*)d_in[13];
  const float* m3 = (const float*)d_in[14];
  const float* v3 = (const float*)d_in[15];
  const int* nz = (const int*)d_in[16];
  const int* ny = (const int*)d_in[17];
  const int* nx = (const int*)d_in[18];
  float* out = (float*)d_out;

  const size_t wf_bytes = 288u * 1024u;                              // 294912
  const size_t bn_bytes = 4096u;                                     // 6*128*4 padded
  const size_t fb_bytes = ((size_t)NVOX + 1) * CCH * sizeof(short);  // 67.1 MB
  if (ws_size >= wf_bytes + bn_bytes + fb_bytes) {
    unsigned short* wf  = (unsigned short*)d_ws;
    float*          bnt = (float*)((char*)d_ws + wf_bytes);
    unsigned short* fbf = (unsigned short*)((char*)d_ws + wf_bytes + bn_bytes);
    hipLaunchKernelGGL(prep_wfrag, dim3(288), dim3(64), 0, stream, W1, W2, W3, wf);
    hipLaunchKernelGGL(prep_bn, dim3(1), dim3(CCH), 0, stream,
                       g0, b0, m0, v0, g2, b2, m2, v2, g3, b3, m3, v3, bnt);
    hipLaunchKernelGGL(prep_bf16, dim3((NVOX * CCH) / (256 * 8)), dim3(256), 0, stream,
                       feats, fbf);
    hipLaunchKernelGGL(recon_v14, dim3((NVOX / 256) * 2), dim3(1024), 0, stream,
                       fbf, wf, bnt, nz, nx, ny, out);
  } else {
    hipLaunchKernelGGL(recon_naive, dim3(NVOX), dim3(CCH), 0, stream,
                       feats, W1, W2, W3, nz, ny, nx,
                       g0, b0, m0, v0, g2, b2, m2, v2, g3, b3, m3, v3, out);
  }
}

// Round 17
// 140.666 us; speedup vs baseline: 1.3148x; 1.1533x over previous
//
#include <hip/hip_runtime.h>
#include <hip/hip_bf16.h>
#include <stdint.h>
#include <stddef.h>

#define NVOX 262144
#define CCH 128
#define BN_EPS 1e-3f

typedef __attribute__((ext_vector_type(8))) short bfrag;   // 8 bf16 = 4 VGPRs
typedef __attribute__((ext_vector_type(4))) float f4;      // 4 f32

#define AS1 __attribute__((address_space(1)))
#define AS3 __attribute__((address_space(3)))

__device__ __forceinline__ unsigned short f2bf(float f) {
  union { float f; unsigned u; } v; v.f = f;
  unsigned r = v.u + 0x7fffu + ((v.u >> 16) & 1u);   // RNE (inputs finite)
  return (unsigned short)(r >> 16);
}

__device__ __forceinline__ bfrag pack8(f4 x, f4 y) {
  bfrag r;
  r[0] = (short)f2bf(x[0]); r[1] = (short)f2bf(x[1]);
  r[2] = (short)f2bf(x[2]); r[3] = (short)f2bf(x[3]);
  r[4] = (short)f2bf(y[0]); r[5] = (short)f2bf(y[1]);
  r[6] = (short)f2bf(y[2]); r[7] = (short)f2bf(y[3]);
  return r;
}

// minimal-op sigmoid via LLVM intrinsics: rcp(1 + 2^(-x*log2(e))).
// 2 VALU + 2 TRANS; rcp ~1ulp -- fine vs the 0.2775 absmax threshold.
__device__ __forceinline__ float sigmoidf_(float x) {
  const float e = __builtin_amdgcn_exp2f(x * -1.44269504f);
  return __builtin_amdgcn_rcpf(1.f + e);
}

__device__ __forceinline__ float bf2f(unsigned short h) {
  union { unsigned u; float f; } v; v.u = ((unsigned)h) << 16; return v.f;
}

// ---------------------------------------------------------------------------
// Pre-swizzle W1/W2/W3 into MFMA B-fragment order, bf16:
// region r = conv*3+tap (conv: 0=W1, 1=W2, 2=W3); frag = (r*4 + kc)*8 + tile
// lane holds B[k = kc*32 + (lane>>4)*8 + e][col = tile*16 + (lane&15)]
// ---------------------------------------------------------------------------
__global__ void prep_wfrag(const float* __restrict__ W1, const float* __restrict__ W2,
                           const float* __restrict__ W3, unsigned short* __restrict__ wf) {
  const int frag = blockIdx.x;           // 0..287
  const int tile = frag & 7;
  const int kc   = (frag >> 3) & 3;
  const int tap  = (frag >> 5) % 3;
  const int conv = frag / 96;
  const float* W = (conv == 0) ? W1 : ((conv == 1) ? W2 : W3);
  const int l   = threadIdx.x;           // 0..63
  const int col = tile * 16 + (l & 15);
  const int k0  = kc * 32 + (l >> 4) * 8;
  bfrag o;
#pragma unroll
  for (int e = 0; e < 8; ++e)
    o[e] = (short)f2bf(W[(size_t)(tap * CCH + k0 + e) * CCH + col]);
  *reinterpret_cast<bfrag*>(wf + (size_t)frag * 512 + l * 8) = o;
}

// ---------------------------------------------------------------------------
// BN scale/shift tables: bn[6][128] = {sc0, sh0, sc2, sh2, sc3, sh3}
// ---------------------------------------------------------------------------
__global__ void prep_bn(const float* g0, const float* b0, const float* m0, const float* v0,
                        const float* g2, const float* b2, const float* m2, const float* v2,
                        const float* g3, const float* b3, const float* m3, const float* v3,
                        float* __restrict__ bn) {
  const int c = threadIdx.x;
  const float s0 = g0[c] * rsqrtf(v0[c] + BN_EPS);
  const float s2 = g2[c] * rsqrtf(v2[c] + BN_EPS);
  const float s3 = g3[c] * rsqrtf(v3[c] + BN_EPS);
  bn[0 * CCH + c] = s0; bn[1 * CCH + c] = b0[c] - m0[c] * s0;
  bn[2 * CCH + c] = s2; bn[3 * CCH + c] = b2[c] - m2[c] * s2;
  bn[4 * CCH + c] = s3; bn[5 * CCH + c] = b3[c] - m3[c] * s3;
}

// ---------------------------------------------------------------------------
// Features fp32 -> bf16 (row N = zeros, the sentinel row)
// ---------------------------------------------------------------------------
__global__ void prep_bf16(const float* __restrict__ feats, unsigned short* __restrict__ fbf) {
  const size_t base = ((size_t)blockIdx.x * 256 + threadIdx.x) * 8;
  const f4 x = *reinterpret_cast<const f4*>(feats + base);
  const f4 y = *reinterpret_cast<const f4*>(feats + base + 4);
  *reinterpret_cast<bfrag*>(fbf + base) = pack8(x, y);
  if (blockIdx.x == 0 && threadIdx.x < 16) {
    bfrag z = {0, 0, 0, 0, 0, 0, 0, 0};
    *reinterpret_cast<bfrag*>(fbf + (size_t)NVOX * CCH + threadIdx.x * 8) = z;
  }
}

// ---------------------------------------------------------------------------
// v17 = v11 VERBATIM (125 us main, VGPR 60, proven geometry:
// row0 = (bid>>1)*128, grid (NVOX/128)*2) + intrinsic fast sigmoid only.
// [v15/v16 failed from a copy-paste geometry bug: 256-row block stride with
//  only 128 rows of wave coverage -- half the output never written.]
// Structure: 512 threads = 8 waves x 16 rows x 64 cols = 128 rows/block,
// B per conv in 48 KB LDS (refilled twice; 3 blocks/CU by LDS), wave-uniform
// sparsity skip, first-valid off-center gather preissued before the self tap,
// folded activations, bf16 feature mirror + epilogue.
// ---------------------------------------------------------------------------
__global__ __launch_bounds__(512, 4)
void recon_v17(const unsigned short* __restrict__ fbf,
               const unsigned short* __restrict__ wfrag,
               const float* __restrict__ bn,
               const int* __restrict__ nbrz, const int* __restrict__ nbrx,
               const int* __restrict__ nbry,
               float* __restrict__ out) {
  __shared__ unsigned short Bb[24576];   // 48 KB: 3 slots x 16 frags x 1 KB

  const int tid  = threadIdx.x;
  const int lane = tid & 63;
  const int w    = tid >> 6;        // wave 0..7
  const int l15  = lane & 15;
  const int lhi  = lane >> 4;       // 0..3
  const int cb   = blockIdx.x & 1;  // 64-col half
  const int row0 = (blockIdx.x >> 1) * 128;   // v11 geometry: 128 rows/block
  const int wrow = row0 + w * 16;

  // Fill the 3 resident slots for one conv (region base RB: W1=0, W2=3, W3=6).
  auto fillconv = [&](int RB) {
#pragma unroll
    for (int i = 0; i < 6; ++i) {
      const int L    = w * 6 + i;        // local frag 0..47
      const int slot = L >> 4;           // tap 0..2
      const int sub  = L & 15;           // kc*4+ct
      const int g    = ((RB + slot) * 4 + (sub >> 2)) * 8 + cb * 4 + (sub & 3);
      __builtin_amdgcn_global_load_lds(
          (const AS1 void*)(wfrag + (size_t)g * 512 + lane * 8),
          (AS3 void*)((char*)Bb + L * 1024), 16, 0, 0);
    }
  };

  // ---- prologue: conv-z fill + neighbor indices + self-row fragments ----
  fillconv(0);
  const int row = wrow + l15;
  const int rg  = row * 3;
  const int izp = nbrz[rg + 0], izn = nbrz[rg + 2];
  const int ixp = nbrx[rg + 0], ixn = nbrx[rg + 2];
  const int iyp = nbry[rg + 0], iyn = nbry[rg + 2];

  const bool azp = __any(izp != NVOX), azn = __any(izn != NVOX);
  const bool axp = __any(ixp != NVOX), axn = __any(ixn != NVOX);
  const bool ayp = __any(iyp != NVOX), ayn = __any(iyn != NVOX);

  bfrag aF[4];   // gathered-neighbor fragments
  bfrag aS[4];   // self-row fragments (reused by all 3 center taps)

#define LOADF(DST, IDX) {                                                     \
    const char* p = (const char*)fbf + ((size_t)(unsigned)(IDX) << 8) + (lhi << 4); \
    DST[0] = *reinterpret_cast<const bfrag*>(p);                              \
    DST[1] = *reinterpret_cast<const bfrag*>(p + 64);                         \
    DST[2] = *reinterpret_cast<const bfrag*>(p + 128);                        \
    DST[3] = *reinterpret_cast<const bfrag*>(p + 192);                        \
  }

#define TAP(SLOT, AFR, ACCS) {                                                \
    const char* bs = (const char*)Bb + (SLOT) * 16384 + lane * 16;            \
    _Pragma("unroll")                                                         \
    for (int kc = 0; kc < 4; ++kc) {                                          \
      _Pragma("unroll")                                                       \
      for (int ct = 0; ct < 4; ++ct) {                                        \
        const bfrag b = *reinterpret_cast<const bfrag*>(                      \
            bs + (kc * 4 + ct) * 1024);                                       \
        ACCS[ct] = __builtin_amdgcn_mfma_f32_16x16x32_bf16(                   \
            AFR[kc], b, ACCS[ct], 0, 0, 0);                                   \
      } } }

  // One conv: preload first valid off-center; self tap covers its latency.
#define CONV(VP, VN, IP, IN, ACCS)                                            \
  {                                                                           \
    if (VP)      LOADF(aF, IP)                                                \
    else if (VN) LOADF(aF, IN)                                                \
    TAP(1, aS, ACCS)                                                          \
    if (VP) {                                                                 \
      TAP(0, aF, ACCS)                                                        \
      if (VN) { LOADF(aF, IN)  TAP(2, aF, ACCS) }                             \
    } else if (VN) {                                                          \
      TAP(2, aF, ACCS)                                                        \
    }                                                                         \
  }

  LOADF(aS, row)   // self row (sentinel-free), reused by the 3 center taps

  __syncthreads();   // conv-z B ready (syncthreads drains the load-lds queue)

  f4 acc[4], run[4];
#pragma unroll
  for (int ct = 0; ct < 4; ++ct) {
    acc[ct] = f4{0.f, 0.f, 0.f, 0.f};
    run[ct] = f4{0.f, 0.f, 0.f, 0.f};
  }

  // ================= conv-z (W1) =================
  CONV(azp, azn, izp, izn, acc)
  __syncthreads();            // conv-z B readers done
  fillconv(6);                // issue conv-x (W3) fill; fold hides some latency
  // fold: run = sigmoid(bn2(sigmoid(bn0(acc)))); acc = 0
#pragma unroll
  for (int ct = 0; ct < 4; ++ct) {
    const int col = cb * 64 + ct * 16 + l15;
    const float sc0 = bn[0 * CCH + col], sh0 = bn[1 * CCH + col];
    const float sc2 = bn[2 * CCH + col], sh2 = bn[3 * CCH + col];
#pragma unroll
    for (int j = 0; j < 4; ++j) {
      const float u = sigmoidf_(sc0 * acc[ct][j] + sh0);
      run[ct][j] = sigmoidf_(sc2 * u + sh2);
    }
    acc[ct] = f4{0.f, 0.f, 0.f, 0.f};
  }
  __syncthreads();            // conv-x B ready

  // ================= conv-x (W3) =================
  CONV(axp, axn, ixp, ixn, acc)
  __syncthreads();            // conv-x B readers done
  fillconv(3);                // issue conv-y (W2) fill
  // fold: run += sigmoid(bn3(acc))
#pragma unroll
  for (int ct = 0; ct < 4; ++ct) {
    const int col = cb * 64 + ct * 16 + l15;
    const float sc3 = bn[4 * CCH + col], sh3 = bn[5 * CCH + col];
#pragma unroll
    for (int j = 0; j < 4; ++j)
      run[ct][j] += sigmoidf_(sc3 * acc[ct][j] + sh3);
  }
  __syncthreads();            // conv-y B ready

  // ================= conv-y (W2), raw into run =================
  CONV(ayp, ayn, iyp, iyn, run)

#undef CONV
#undef TAP
#undef LOADF

  // ---- epilogue: multiply by features (bf16, cache-hot), store fp32 ----
#pragma unroll
  for (int ct = 0; ct < 4; ++ct) {
    const int col = cb * 64 + ct * 16 + l15;
#pragma unroll
    for (int j = 0; j < 4; ++j) {
      const int r = wrow + (lhi << 2) + j;
      const size_t o = ((size_t)r << 7) + col;
      out[o] = run[ct][j] * bf2f(fbf[o]);
    }
  }
}

// ---------------------------------------------------------------------------
// Last-resort fallback: exact fp32
// ---------------------------------------------------------------------------
__global__ void recon_naive(const float* __restrict__ feats,
    const float* __restrict__ W1, const float* __restrict__ W2, const float* __restrict__ W3,
    const int* __restrict__ nbrz, const int* __restrict__ nbry, const int* __restrict__ nbrx,
    const float* g0, const float* b0, const float* m0, const float* v0,
    const float* g2, const float* b2, const float* m2, const float* v2,
    const float* g3, const float* b3, const float* m3, const float* v3,
    float* __restrict__ out) {
  __shared__ float rows[3][CCH];
  const int n = blockIdx.x;
  const int d = threadIdx.x;
  float res[3];
#pragma unroll
  for (int conv = 0; conv < 3; ++conv) {
    const int* nbr  = (conv == 0) ? nbrz : ((conv == 1) ? nbry : nbrx);
    const float* W  = (conv == 0) ? W1 : ((conv == 1) ? W2 : W3);
#pragma unroll
    for (int tap = 0; tap < 3; ++tap) {
      const int idx = nbr[n * 3 + tap];
      rows[tap][d] = ((unsigned)idx < (unsigned)NVOX) ? feats[((size_t)idx << 7) + d] : 0.f;
    }
    __syncthreads();
    const float* rflat = &rows[0][0];
    float s = 0.f;
    for (int k = 0; k < 3 * CCH; ++k) s += rflat[k] * W[(size_t)k * CCH + d];
    res[conv] = s;
    __syncthreads();
  }
  const float sc0 = g0[d] * rsqrtf(v0[d] + BN_EPS), sh0 = b0[d] - m0[d] * sc0;
  const float sc2 = g2[d] * rsqrtf(v2[d] + BN_EPS), sh2 = b2[d] - m2[d] * sc2;
  const float sc3 = g3[d] * rsqrtf(v3[d] + BN_EPS), sh3 = b3[d] - m3[d] * sc3;
  float u = 1.f / (1.f + __expf(-(sc0 * res[0] + sh0)));
  u = 1.f / (1.f + __expf(-(sc2 * u + sh2)));
  const float s3v = 1.f / (1.f + __expf(-(sc3 * res[2] + sh3)));
  out[((size_t)n << 7) + d] = (u + res[1] + s3v) * feats[((size_t)n << 7) + d];
}

extern "C" void kernel_launch(void* const* d_in, const int* in_sizes, int n_in,
                              void* d_out, int out_size, void* d_ws, size_t ws_size,
                              hipStream_t stream) {
  const float* feats = (const float*)d_in[0];
  const float* W1 = (const float*)d_in[1];
  const float* W2 = (const float*)d_in[2];
  const float* W3 = (const float*)d_in[3];
  const float* g0 = (const float*)d_in[4];
  const float* b0 = (const float*)d_in[5];
  const float* m0 = (const float*)d_in[6];
  const float* v0 = (const float*)d_in[7];
  const float* g2 = (const float*)d_in[8];
  const float* b2 = (const float*)d_in[9];
  const float* m2 = (const float*)d_in[10];
  const float* v2 = (const float*)d_in[11];
  const float* g3 = (const float*)d_in[12];
  const float* b3 = (const float*)d_in[13];
  const float* m3 = (const float*)d_in[14];
  const float* v3 = (const float*)d_in[15];
  const int* nz = (const int*)d_in[16];
  const int* ny = (const int*)d_in[17];
  const int* nx = (const int*)d_in[18];
  float* out = (float*)d_out;

  const size_t wf_bytes = 288u * 1024u;                              // 294912
  const size_t bn_bytes = 4096u;                                     // 6*128*4 padded
  const size_t fb_bytes = ((size_t)NVOX + 1) * CCH * sizeof(short);  // 67.1 MB
  if (ws_size >= wf_bytes + bn_bytes + fb_bytes) {
    unsigned short* wf  = (unsigned short*)d_ws;
    float*          bnt = (float*)((char*)d_ws + wf_bytes);
    unsigned short* fbf = (unsigned short*)((char*)d_ws + wf_bytes + bn_bytes);
    hipLaunchKernelGGL(prep_wfrag, dim3(288), dim3(64), 0, stream, W1, W2, W3, wf);
    hipLaunchKernelGGL(prep_bn, dim3(1), dim3(CCH), 0, stream,
                       g0, b0, m0, v0, g2, b2, m2, v2, g3, b3, m3, v3, bnt);
    hipLaunchKernelGGL(prep_bf16, dim3((NVOX * CCH) / (256 * 8)), dim3(256), 0, stream,
                       feats, fbf);
    hipLaunchKernelGGL(recon_v17, dim3((NVOX / 128) * 2), dim3(512), 0, stream,
                       fbf, wf, bnt, nz, nx, ny, out);
  } else {
    hipLaunchKernelGGL(recon_naive, dim3(NVOX), dim3(CCH), 0, stream,
                       feats, W1, W2, W3, nz, ny, nx,
                       g0, b0, m0, v0, g2, b2, m2, v2, g3, b3, m3, v3, out);
  }
}